// Round 15
// baseline (5698.164 us; speedup 1.0000x reference)
//
#include <hip/hip_runtime.h>
#include <math.h>

#define NCH 96          // HID_C == OUT_C == 96
#define SCAN_TILE 2048  // 256 threads x 8 elements

typedef __attribute__((ext_vector_type(8))) short short8;
typedef __attribute__((ext_vector_type(4))) float f32x4;
typedef unsigned short ushort_t;
typedef unsigned int uint_t;

// round-to-nearest-even fp32 -> bf16 bits
__device__ __forceinline__ uint_t bf16_rne(float f) {
    uint_t u = __builtin_bit_cast(uint_t, f);
    return (u + 0x7FFFu + ((u >> 16) & 1u)) >> 16;
}

__device__ __forceinline__ void unp2(uint_t u, float& lo, float& hi) {
    lo = __builtin_bit_cast(float, u << 16);
    hi = __builtin_bit_cast(float, u & 0xFFFF0000u);
}

// ---------------------------------------------------------------------------
__global__ void count_kernel(const int* __restrict__ dst, int* __restrict__ cnt, int E) {
    int e = blockIdx.x * blockDim.x + threadIdx.x;
    if (e < E) atomicAdd(&cnt[dst[e]], 1);
}

// ---- multi-block exclusive scan, phase A: per-block sums ----
__global__ __launch_bounds__(256) void scanA_kernel(const int* __restrict__ cnt,
                                                    int* __restrict__ bsum, int n) {
    int b = blockIdx.x, t = threadIdx.x;
    int base = b * SCAN_TILE;
    int s = 0;
    for (int i = t; i < SCAN_TILE; i += 256) {
        int idx = base + i;
        if (idx < n) s += cnt[idx];
    }
#pragma unroll
    for (int off = 32; off; off >>= 1) s += __shfl_down(s, off, 64);
    __shared__ int red[4];
    if ((t & 63) == 0) red[t >> 6] = s;
    __syncthreads();
    if (t == 0) bsum[b] = red[0] + red[1] + red[2] + red[3];
}

// ---- phase B: exclusive scan of block sums (nb <= 256); rowptrN = total ----
__global__ __launch_bounds__(256) void scanB_kernel(int* __restrict__ bsum,
                                                    int* __restrict__ rowptrN, int nb) {
    int t = threadIdx.x;
    __shared__ int ps[256];
    int v = (t < nb) ? bsum[t] : 0;
    ps[t] = v;
    __syncthreads();
    for (int off = 1; off < 256; off <<= 1) {
        int add = (t >= off) ? ps[t - off] : 0;
        __syncthreads();
        ps[t] += add;
        __syncthreads();
    }
    if (t < nb) bsum[t] = ps[t] - v;     // exclusive prefix
    if (t == nb - 1) rowptrN[0] = ps[t]; // total = E
}

// ---- phase C: block-local scan -> rowptr, fill cursor (in cnt), dinv ----
__global__ __launch_bounds__(256) void scanC_kernel(int* __restrict__ cnt,
                                                    const int* __restrict__ bsum,
                                                    int* __restrict__ rowptr,
                                                    float* __restrict__ dinv, int n) {
    int b = blockIdx.x, t = threadIdx.x;
    int base = b * SCAN_TILE + t * 8;
    int c[8];
    int s = 0;
#pragma unroll
    for (int j = 0; j < 8; ++j) {
        int idx = base + j;
        c[j] = (idx < n) ? cnt[idx] : 0;
        s += c[j];
    }
    __shared__ int ps[256];
    ps[t] = s;
    __syncthreads();
    for (int off = 1; off < 256; off <<= 1) {
        int add = (t >= off) ? ps[t - off] : 0;
        __syncthreads();
        ps[t] += add;
        __syncthreads();
    }
    int run = bsum[b] + ps[t] - s;
#pragma unroll
    for (int j = 0; j < 8; ++j) {
        int idx = base + j;
        if (idx < n) {
            rowptr[idx] = run;
            cnt[idx] = run;                        // fill cursor
            dinv[idx] = rsqrtf((float)(c[j] + 1)); // self-loop degree
            run += c[j];
        }
    }
}

// ---------------------------------------------------------------------------
// Hybrid: blocks [0, gemmBlocks) do layer-1 GEMM (K=128, no BN);
// blocks [gemmBlocks, ...) do CSR adj fill. Both depend only on scanC ->
// they overlap on the CUs instead of serializing (~55us fill hidden).
// ---------------------------------------------------------------------------
__global__ __launch_bounds__(256) void gemm1_fill(const float* __restrict__ x,
                                                  const float* __restrict__ W,
                                                  const float* __restrict__ dinv,
                                                  ushort_t* __restrict__ hs, int n,
                                                  int gemmBlocks,
                                                  const int* __restrict__ ei,
                                                  int* __restrict__ fill,
                                                  int* __restrict__ adj, int E) {
    constexpr int K = 128;
    constexpr int NKS = K / 32;
    constexpr int NFR = NKS * 6 * 512;
    __shared__ short BH[NFR];
    __shared__ short BL[NFR];

    if (blockIdx.x >= gemmBlocks) {
        // ---- fill path: int atomics on 50K cursors (~16 edges/cursor) ----
        int e = (blockIdx.x - gemmBlocks) * 256 + threadIdx.x;
        if (e < E) {
            int s = ei[e];
            int pos = atomicAdd(&fill[ei[E + e]], 1);
            adj[pos] = s;
        }
        return;
    }

    const int tid = threadIdx.x;
    // ---- W fragments (coalesced read, hi/lo split) ----
    for (int w = tid; w < K * NCH; w += 256) {
        float wv = W[w];
        int k = w / NCH;
        int col = w - k * NCH;
        int ks = k >> 5, kin = k & 31;
        int idx = ((ks * 6 + (col >> 4)) << 9) + (((kin >> 3) * 16 + (col & 15)) << 3) + (kin & 7);
        uint_t hb = bf16_rne(wv);
        float hf = __builtin_bit_cast(float, hb << 16);
        uint_t lb = bf16_rne(wv - hf);
        BH[idx] = (short)hb;
        BL[idx] = (short)lb;
    }
    __syncthreads();

    const int l  = tid & 63;
    const int wv_ = tid >> 6;
    const int r0 = blockIdx.x * 128 + wv_ * 32;
    const int klo = (l >> 4) << 3;

    f32x4 acc[2][6] = {};

    for (int ks = 0; ks < NKS; ++ks) {
        short8 Ah[2], Al[2];
#pragma unroll
        for (int rt = 0; rt < 2; ++rt) {
            int rg = r0 + rt * 16 + (l & 15);
            rg = rg < n ? rg : n - 1;
            const float* px = x + (size_t)rg * K + ks * 32 + klo;
            float4 f0 = *(const float4*)px;
            float4 f1 = *(const float4*)(px + 4);
            float vv[8] = {f0.x, f0.y, f0.z, f0.w, f1.x, f1.y, f1.z, f1.w};
#pragma unroll
            for (int i = 0; i < 8; ++i) {
                float v = vv[i];
                uint_t hb = bf16_rne(v);
                float hf = __builtin_bit_cast(float, hb << 16);
                uint_t lb = bf16_rne(v - hf);
                Ah[rt][i] = (short)hb;
                Al[rt][i] = (short)lb;
            }
        }
#pragma unroll
        for (int ct = 0; ct < 6; ++ct) {
            int off = ((ks * 6 + ct) << 9) + (l << 3);
            short8 bh = *(const short8*)&BH[off];
            short8 bl = *(const short8*)&BL[off];
#pragma unroll
            for (int rt = 0; rt < 2; ++rt) {
                acc[rt][ct] = __builtin_amdgcn_mfma_f32_16x16x32_bf16(Ah[rt], bh, acc[rt][ct], 0, 0, 0);
                acc[rt][ct] = __builtin_amdgcn_mfma_f32_16x16x32_bf16(Al[rt], bh, acc[rt][ct], 0, 0, 0);
                acc[rt][ct] = __builtin_amdgcn_mfma_f32_16x16x32_bf16(Ah[rt], bl, acc[rt][ct], 0, 0, 0);
            }
        }
    }

#pragma unroll
    for (int rt = 0; rt < 2; ++rt) {
#pragma unroll
        for (int i = 0; i < 4; ++i) {
            int row = r0 + rt * 16 + ((l >> 4) << 2) + i;
            if (row < n) {
                float dv = dinv[row];
#pragma unroll
                for (int ct = 0; ct < 6; ++ct) {
                    float v = acc[rt][ct][i] * dv;
                    hs[(size_t)row * NCH + ct * 16 + (l & 15)] = (ushort_t)bf16_rne(v);
                }
            }
        }
    }
}

// ---------------------------------------------------------------------------
// MFMA GEMM (split-bf16): hs[r][c] = bf16((in[r][:]@W[:][c]) * dinv[r])
// BN params computed in-prologue from sums/g/bt; relu(t*a+b) on A-load
// ---------------------------------------------------------------------------
template <int K>
__global__ __launch_bounds__(256) void gemm_mfma_bn(const float* __restrict__ x,
                                                    const float* __restrict__ sums,
                                                    const float* __restrict__ g,
                                                    const float* __restrict__ bt,
                                                    float fn,
                                                    const float* __restrict__ W,
                                                    const float* __restrict__ dinv,
                                                    ushort_t* __restrict__ hs, int n) {
    constexpr int NKS = K / 32;
    constexpr int NFR = NKS * 6 * 512;
    __shared__ short BH[NFR];
    __shared__ short BL[NFR];
    __shared__ float ABl[2 * NCH];

    const int tid = threadIdx.x;
    for (int w = tid; w < K * NCH; w += 256) {
        float wv = W[w];
        int k = w / NCH;
        int col = w - k * NCH;
        int ks = k >> 5, kin = k & 31;
        int idx = ((ks * 6 + (col >> 4)) << 9) + (((kin >> 3) * 16 + (col & 15)) << 3) + (kin & 7);
        uint_t hb = bf16_rne(wv);
        float hf = __builtin_bit_cast(float, hb << 16);
        uint_t lb = bf16_rne(wv - hf);
        BH[idx] = (short)hb;
        BL[idx] = (short)lb;
    }
    if (tid < NCH) {
        float mean = sums[tid] / fn;
        float var = sums[NCH + tid] / fn - mean * mean;
        float a = g[tid] * rsqrtf(var + 1e-5f);
        ABl[tid] = a;
        ABl[NCH + tid] = bt[tid] - mean * a;
    }
    __syncthreads();

    const int l  = tid & 63;
    const int wv_ = tid >> 6;
    const int r0 = blockIdx.x * 128 + wv_ * 32;
    const int klo = (l >> 4) << 3;

    f32x4 acc[2][6] = {};

    for (int ks = 0; ks < NKS; ++ks) {
        float av[8], bv[8];
        int kb = ks * 32 + klo;
#pragma unroll
        for (int i = 0; i < 8; ++i) { av[i] = ABl[kb + i]; bv[i] = ABl[NCH + kb + i]; }
        short8 Ah[2], Al[2];
#pragma unroll
        for (int rt = 0; rt < 2; ++rt) {
            int rg = r0 + rt * 16 + (l & 15);
            rg = rg < n ? rg : n - 1;
            const float* px = x + (size_t)rg * K + ks * 32 + klo;
            float4 f0 = *(const float4*)px;
            float4 f1 = *(const float4*)(px + 4);
            float vv[8] = {f0.x, f0.y, f0.z, f0.w, f1.x, f1.y, f1.z, f1.w};
#pragma unroll
            for (int i = 0; i < 8; ++i) {
                float v = fmaxf(fmaf(vv[i], av[i], bv[i]), 0.0f);
                uint_t hb = bf16_rne(v);
                float hf = __builtin_bit_cast(float, hb << 16);
                uint_t lb = bf16_rne(v - hf);
                Ah[rt][i] = (short)hb;
                Al[rt][i] = (short)lb;
            }
        }
#pragma unroll
        for (int ct = 0; ct < 6; ++ct) {
            int off = ((ks * 6 + ct) << 9) + (l << 3);
            short8 bh = *(const short8*)&BH[off];
            short8 bl = *(const short8*)&BL[off];
#pragma unroll
            for (int rt = 0; rt < 2; ++rt) {
                acc[rt][ct] = __builtin_amdgcn_mfma_f32_16x16x32_bf16(Ah[rt], bh, acc[rt][ct], 0, 0, 0);
                acc[rt][ct] = __builtin_amdgcn_mfma_f32_16x16x32_bf16(Al[rt], bh, acc[rt][ct], 0, 0, 0);
                acc[rt][ct] = __builtin_amdgcn_mfma_f32_16x16x32_bf16(Ah[rt], bl, acc[rt][ct], 0, 0, 0);
            }
        }
    }

#pragma unroll
    for (int rt = 0; rt < 2; ++rt) {
#pragma unroll
        for (int i = 0; i < 4; ++i) {
            int row = r0 + rt * 16 + ((l >> 4) << 2) + i;
            if (row < n) {
                float dv = dinv[row];
#pragma unroll
                for (int ct = 0; ct < 6; ++ct) {
                    float v = acc[rt][ct][i] * dv;
                    hs[(size_t)row * NCH + ct * 16 + (l & 15)] = (ushort_t)bf16_rne(v);
                }
            }
        }
    }
}

// ---------------------------------------------------------------------------
// gather + fused BN stats, quarter-wave version:
// 16 lanes per node, each lane owns 6 channels (dwordx3 = 12B = exactly 192B/row).
// 4 nodes/wave x 2 unrolled chains = 8 outstanding gathers/wave; no LDS.
// t[i] = dinv[i]*(hs[i] + sum hs[adj]); sums += {t, t^2} via shfl+atomics.
// ---------------------------------------------------------------------------
__global__ __launch_bounds__(256) void gather_stats(const int* __restrict__ rowptr,
                                                    const int* __restrict__ adj,
                                                    const float* __restrict__ dinv,
                                                    const ushort_t* __restrict__ HS,
                                                    float* __restrict__ AGG,
                                                    float* __restrict__ sums, int n) {
    const int tid = threadIdx.x;
    const int qw = tid >> 4;        // 0..15 quarter-wave id in block
    const int lane = tid & 15;      // 0..15: channels [lane*6, lane*6+6)
    const uint_t* HSu = (const uint_t*)HS;
    const int l3 = lane * 3;

    float s1[6] = {0.f, 0.f, 0.f, 0.f, 0.f, 0.f};
    float s2[6] = {0.f, 0.f, 0.f, 0.f, 0.f, 0.f};

    const int node = blockIdx.x * 16 + qw;
    if (node < n) {
        int lo = rowptr[node], hi = rowptr[node + 1];
        float dv = dinv[node];
        float a[6], b[6] = {0.f, 0.f, 0.f, 0.f, 0.f, 0.f};
        {
            uint3 v = *(const uint3*)(HSu + (size_t)node * 48 + l3);  // self
            unp2(v.x, a[0], a[1]); unp2(v.y, a[2], a[3]); unp2(v.z, a[4], a[5]);
        }
        int j = lo;
        for (; j + 1 < hi; j += 2) {
            int e0 = adj[j], e1 = adj[j + 1];
            uint3 v0 = *(const uint3*)(HSu + (size_t)e0 * 48 + l3);
            uint3 v1 = *(const uint3*)(HSu + (size_t)e1 * 48 + l3);
            float f0, f1;
            unp2(v0.x, f0, f1); a[0] += f0; a[1] += f1;
            unp2(v0.y, f0, f1); a[2] += f0; a[3] += f1;
            unp2(v0.z, f0, f1); a[4] += f0; a[5] += f1;
            unp2(v1.x, f0, f1); b[0] += f0; b[1] += f1;
            unp2(v1.y, f0, f1); b[2] += f0; b[3] += f1;
            unp2(v1.z, f0, f1); b[4] += f0; b[5] += f1;
        }
        if (j < hi) {
            int e0 = adj[j];
            uint3 v0 = *(const uint3*)(HSu + (size_t)e0 * 48 + l3);
            float f0, f1;
            unp2(v0.x, f0, f1); a[0] += f0; a[1] += f1;
            unp2(v0.y, f0, f1); a[2] += f0; a[3] += f1;
            unp2(v0.z, f0, f1); a[4] += f0; a[5] += f1;
        }
        float* row = AGG + (size_t)node * NCH + lane * 6;
        float2 st;
#pragma unroll
        for (int k = 0; k < 6; ++k) {
            float t = (a[k] + b[k]) * dv;
            s1[k] += t;
            s2[k] = fmaf(t, t, s2[k]);
            if (k & 1) { st.y = t; *(float2*)(row + k - 1) = st; }
            else st.x = t;
        }
    }

    // wave reduce: lanes (w&15)==lane across the 4 quarter-waves hold same channels
#pragma unroll
    for (int k = 0; k < 6; ++k) {
        s1[k] += __shfl_xor(s1[k], 16, 64); s1[k] += __shfl_xor(s1[k], 32, 64);
        s2[k] += __shfl_xor(s2[k], 16, 64); s2[k] += __shfl_xor(s2[k], 32, 64);
    }
    if ((tid & 63) < 16) {
#pragma unroll
        for (int k = 0; k < 6; ++k) {
            atomicAdd(&sums[lane * 6 + k], s1[k]);        // non-returning: pipelined
            atomicAdd(&sums[NCH + lane * 6 + k], s2[k]);
        }
    }
}

// fused BN-param + BN-apply + ReLU + column-sum pool (y never materialized)
__global__ __launch_bounds__(384) void apply_pool_kernel(const float* __restrict__ t,
                                                         const float* __restrict__ sums,
                                                         const float* __restrict__ g,
                                                         const float* __restrict__ bt,
                                                         float fn,
                                                         float* __restrict__ pool, int n) {
    int c = threadIdx.x, ry = threadIdx.y;
    __shared__ float A[NCH], B[NCH];
    if (ry == 0) {
        float mean = sums[c] / fn;
        float var = sums[NCH + c] / fn - mean * mean;
        float a = g[c] * rsqrtf(var + 1e-5f);
        A[c] = a;
        B[c] = bt[c] - mean * a;
    }
    __syncthreads();
    float a = A[c], b = B[c];
    float s = 0.f;
    for (int r = blockIdx.x * 4 + ry; r < n; r += gridDim.x * 4) {
        float v = t[(size_t)r * NCH + c];
        s += fmaxf(fmaf(v, a, b), 0.f);
    }
    __shared__ float L[4][NCH];
    L[ry][c] = s;
    __syncthreads();
    if (ry == 0) atomicAdd(&pool[c], L[0][c] + L[1][c] + L[2][c] + L[3][c]);
}

// tiny MLP head: 96 -> 128 -> 64 -> 32 -> 1
__global__ __launch_bounds__(128) void mlp_kernel(const float* __restrict__ pool,
        const float* __restrict__ fw1, const float* __restrict__ fb1,
        const float* __restrict__ fw2, const float* __restrict__ fb2,
        const float* __restrict__ fw3, const float* __restrict__ fb3,
        const float* __restrict__ fw4, const float* __restrict__ fb4,
        float* __restrict__ out, float invn) {
    __shared__ float v[NCH], l1[128], l2[64], l3[32];
    int t = threadIdx.x;
    if (t < NCH) v[t] = pool[t] * invn;
    __syncthreads();
    {
        float a = fb1[t];
        for (int k = 0; k < NCH; ++k) a = fmaf(v[k], fw1[k * 128 + t], a);
        l1[t] = fmaxf(a, 0.f);
    }
    __syncthreads();
    if (t < 64) {
        float a = fb2[t];
        for (int k = 0; k < 128; ++k) a = fmaf(l1[k], fw2[k * 64 + t], a);
        l2[t] = fmaxf(a, 0.f);
    }
    __syncthreads();
    if (t < 32) {
        float a = fb3[t];
        for (int k = 0; k < 64; ++k) a = fmaf(l2[k], fw3[k * 32 + t], a);
        l3[t] = fmaxf(a, 0.f);
    }
    __syncthreads();
    if (t == 0) {
        float a = fb4[0];
        for (int k = 0; k < 32; ++k) a = fmaf(l3[k], fw4[k], a);
        out[0] = a;
    }
}

// ---------------------------------------------------------------------------
extern "C" void kernel_launch(void* const* d_in, const int* in_sizes, int n_in,
                              void* d_out, int out_size, void* d_ws, size_t ws_size,
                              hipStream_t stream) {
    const float* x  = (const float*)d_in[0];
    const int*  ei  = (const int*)d_in[1];
    const float* W1 = (const float*)d_in[2];
    // b1/b2/b3 cancel in BatchNorm mean subtraction — unused
    const float* W2 = (const float*)d_in[4];
    const float* W3 = (const float*)d_in[6];
    const float* g1 = (const float*)d_in[8],  *bt1 = (const float*)d_in[9];
    const float* g2 = (const float*)d_in[10], *bt2 = (const float*)d_in[11];
    const float* g3 = (const float*)d_in[12], *bt3 = (const float*)d_in[13];
    const float* fw1 = (const float*)d_in[14], *fb1 = (const float*)d_in[15];
    const float* fw2 = (const float*)d_in[16], *fb2 = (const float*)d_in[17];
    const float* fw3 = (const float*)d_in[18], *fb3 = (const float*)d_in[19];
    const float* fw4 = (const float*)d_in[20], *fb4 = (const float*)d_in[21];
    float* out = (float*)d_out;

    const int N = in_sizes[0] / 128;
    const int E = in_sizes[1] / 2;
    const size_t n96 = (size_t)N * NCH;

    // workspace layout
    float* ws    = (float*)d_ws;
    float* T     = ws;                       // fp32 aggregate   N*96
    ushort_t* HSB = (ushort_t*)(T + n96);    // bf16 hs          N*96
    float* dinv  = T + n96 + n96 / 2;        // N
    float* sums1 = dinv + N;                 // 192
    float* sums2 = sums1 + 2 * NCH;          // 192
    float* sums3 = sums2 + 2 * NCH;          // 192
    float* pool  = sums3 + 2 * NCH;          // 96
    int*   cnt   = (int*)(pool + NCH);       // N (degree -> fill cursor)
    int*   rowptr= cnt + N;                  // N+1
    int*   bsum  = rowptr + N + 1;           // 256
    int*   adj   = bsum + 256;               // E
    const int nsmall = 3 * 2 * NCH + NCH;    // sums1..3 + pool

    dim3 b96(NCH, 4);
    const int gemmGrid = (N + 127) / 128;
    const int fillGrid = (E + 255) / 256;
    const int gathGrid = (N + 15) / 16;      // 1 node per 16-lane quarter-wave
    const int nb = (N + SCAN_TILE - 1) / SCAN_TILE;

    // ---- CSR build + dinv ----
    hipMemsetAsync(sums1, 0, (size_t)nsmall * 4, stream);
    hipMemsetAsync(cnt, 0, (size_t)N * 4, stream);
    count_kernel<<<(E + 255) / 256, 256, 0, stream>>>(ei + E, cnt, E);
    scanA_kernel<<<nb, 256, 0, stream>>>(cnt, bsum, N);
    scanB_kernel<<<1, 256, 0, stream>>>(bsum, rowptr + N, nb);
    scanC_kernel<<<nb, 256, 0, stream>>>(cnt, bsum, rowptr, dinv, N);

    // ---- layer 1 GEMM overlapped with adj fill (both depend only on scanC) ----
    gemm1_fill<<<gemmGrid + fillGrid, 256, 0, stream>>>(x, W1, dinv, HSB, N, gemmGrid,
                                                        ei, cnt, adj, E);
    gather_stats<<<gathGrid, 256, 0, stream>>>(rowptr, adj, dinv, HSB, T, sums1, N);

    // ---- layer 2: 96 -> 96 (BN-param + BN+ReLU fused into GEMM) ----
    gemm_mfma_bn<96><<<gemmGrid, 256, 0, stream>>>(T, sums1, g1, bt1, (float)N,
                                                   W2, dinv, HSB, N);
    gather_stats<<<gathGrid, 256, 0, stream>>>(rowptr, adj, dinv, HSB, T, sums2, N);

    // ---- layer 3: 96 -> 96 ----
    gemm_mfma_bn<96><<<gemmGrid, 256, 0, stream>>>(T, sums2, g2, bt2, (float)N,
                                                   W3, dinv, HSB, N);
    gather_stats<<<gathGrid, 256, 0, stream>>>(rowptr, adj, dinv, HSB, T, sums3, N);

    // ---- fused BN-param + apply + pool, then MLP head ----
    apply_pool_kernel<<<512, b96, 0, stream>>>(T, sums3, g3, bt3, (float)N, pool, N);
    mlp_kernel<<<1, 128, 0, stream>>>(pool, fw1, fb1, fw2, fb2, fw3, fb3,
                                      fw4, fb4, out, 1.0f / (float)N);
}

// Round 17
// 492.819 us; speedup vs baseline: 11.5624x; 11.5624x over previous
//
#include <hip/hip_runtime.h>
#include <math.h>

#define NCH 96          // HID_C == OUT_C == 96
#define SCAN_TILE 2048  // 256 threads x 8 elements

typedef __attribute__((ext_vector_type(8))) short short8;
typedef __attribute__((ext_vector_type(4))) float f32x4;
typedef unsigned short ushort_t;
typedef unsigned int uint_t;

// round-to-nearest-even fp32 -> bf16 bits
__device__ __forceinline__ uint_t bf16_rne(float f) {
    uint_t u = __builtin_bit_cast(uint_t, f);
    return (u + 0x7FFFu + ((u >> 16) & 1u)) >> 16;
}

__device__ __forceinline__ float4 unp(uint2 u) {
    float4 r;
    r.x = __builtin_bit_cast(float, u.x << 16);
    r.y = __builtin_bit_cast(float, u.x & 0xFFFF0000u);
    r.z = __builtin_bit_cast(float, u.y << 16);
    r.w = __builtin_bit_cast(float, u.y & 0xFFFF0000u);
    return r;
}

// ---------------------------------------------------------------------------
__global__ void count_kernel(const int* __restrict__ dst, int* __restrict__ cnt, int E) {
    int e = blockIdx.x * blockDim.x + threadIdx.x;
    if (e < E) atomicAdd(&cnt[dst[e]], 1);
}

// ---- multi-block exclusive scan, phase A: per-block sums ----
__global__ __launch_bounds__(256) void scanA_kernel(const int* __restrict__ cnt,
                                                    int* __restrict__ bsum, int n) {
    int b = blockIdx.x, t = threadIdx.x;
    int base = b * SCAN_TILE;
    int s = 0;
    for (int i = t; i < SCAN_TILE; i += 256) {
        int idx = base + i;
        if (idx < n) s += cnt[idx];
    }
#pragma unroll
    for (int off = 32; off; off >>= 1) s += __shfl_down(s, off, 64);
    __shared__ int red[4];
    if ((t & 63) == 0) red[t >> 6] = s;
    __syncthreads();
    if (t == 0) bsum[b] = red[0] + red[1] + red[2] + red[3];
}

// ---- phase B: exclusive scan of block sums (nb <= 256); rowptrN = total ----
__global__ __launch_bounds__(256) void scanB_kernel(int* __restrict__ bsum,
                                                    int* __restrict__ rowptrN, int nb) {
    int t = threadIdx.x;
    __shared__ int ps[256];
    int v = (t < nb) ? bsum[t] : 0;
    ps[t] = v;
    __syncthreads();
    for (int off = 1; off < 256; off <<= 1) {
        int add = (t >= off) ? ps[t - off] : 0;
        __syncthreads();
        ps[t] += add;
        __syncthreads();
    }
    if (t < nb) bsum[t] = ps[t] - v;     // exclusive prefix
    if (t == nb - 1) rowptrN[0] = ps[t]; // total = E
}

// ---- phase C: block-local scan -> rowptr, fill cursor (in cnt), dinv ----
__global__ __launch_bounds__(256) void scanC_kernel(int* __restrict__ cnt,
                                                    const int* __restrict__ bsum,
                                                    int* __restrict__ rowptr,
                                                    float* __restrict__ dinv, int n) {
    int b = blockIdx.x, t = threadIdx.x;
    int base = b * SCAN_TILE + t * 8;
    int c[8];
    int s = 0;
#pragma unroll
    for (int j = 0; j < 8; ++j) {
        int idx = base + j;
        c[j] = (idx < n) ? cnt[idx] : 0;
        s += c[j];
    }
    __shared__ int ps[256];
    ps[t] = s;
    __syncthreads();
    for (int off = 1; off < 256; off <<= 1) {
        int add = (t >= off) ? ps[t - off] : 0;
        __syncthreads();
        ps[t] += add;
        __syncthreads();
    }
    int run = bsum[b] + ps[t] - s;
#pragma unroll
    for (int j = 0; j < 8; ++j) {
        int idx = base + j;
        if (idx < n) {
            rowptr[idx] = run;
            cnt[idx] = run;                        // fill cursor
            dinv[idx] = rsqrtf((float)(c[j] + 1)); // self-loop degree
            run += c[j];
        }
    }
}

// ---------------------------------------------------------------------------
// Hybrid: blocks [0, gemmBlocks) do layer-1 GEMM (K=128, no BN);
// blocks [gemmBlocks, ...) do CSR adj fill. Both depend only on scanC ->
// they overlap on the CUs instead of serializing (~55us fill hidden).
// ---------------------------------------------------------------------------
__global__ __launch_bounds__(256) void gemm1_fill(const float* __restrict__ x,
                                                  const float* __restrict__ W,
                                                  const float* __restrict__ dinv,
                                                  ushort_t* __restrict__ hs, int n,
                                                  int gemmBlocks,
                                                  const int* __restrict__ ei,
                                                  int* __restrict__ fill,
                                                  int* __restrict__ adj, int E) {
    constexpr int K = 128;
    constexpr int NKS = K / 32;
    constexpr int NFR = NKS * 6 * 512;
    __shared__ short BH[NFR];
    __shared__ short BL[NFR];

    if (blockIdx.x >= gemmBlocks) {
        // ---- fill path: int atomics on 50K cursors (~16 edges/cursor) ----
        int e = (blockIdx.x - gemmBlocks) * 256 + threadIdx.x;
        if (e < E) {
            int s = ei[e];
            int pos = atomicAdd(&fill[ei[E + e]], 1);
            adj[pos] = s;
        }
        return;
    }

    const int tid = threadIdx.x;
    // ---- W fragments (coalesced read, hi/lo split) ----
    for (int w = tid; w < K * NCH; w += 256) {
        float wv = W[w];
        int k = w / NCH;
        int col = w - k * NCH;
        int ks = k >> 5, kin = k & 31;
        int idx = ((ks * 6 + (col >> 4)) << 9) + (((kin >> 3) * 16 + (col & 15)) << 3) + (kin & 7);
        uint_t hb = bf16_rne(wv);
        float hf = __builtin_bit_cast(float, hb << 16);
        uint_t lb = bf16_rne(wv - hf);
        BH[idx] = (short)hb;
        BL[idx] = (short)lb;
    }
    __syncthreads();

    const int l  = tid & 63;
    const int wv_ = tid >> 6;
    const int r0 = blockIdx.x * 128 + wv_ * 32;
    const int klo = (l >> 4) << 3;

    f32x4 acc[2][6] = {};

    for (int ks = 0; ks < NKS; ++ks) {
        short8 Ah[2], Al[2];
#pragma unroll
        for (int rt = 0; rt < 2; ++rt) {
            int rg = r0 + rt * 16 + (l & 15);
            rg = rg < n ? rg : n - 1;
            const float* px = x + (size_t)rg * K + ks * 32 + klo;
            float4 f0 = *(const float4*)px;
            float4 f1 = *(const float4*)(px + 4);
            float vv[8] = {f0.x, f0.y, f0.z, f0.w, f1.x, f1.y, f1.z, f1.w};
#pragma unroll
            for (int i = 0; i < 8; ++i) {
                float v = vv[i];
                uint_t hb = bf16_rne(v);
                float hf = __builtin_bit_cast(float, hb << 16);
                uint_t lb = bf16_rne(v - hf);
                Ah[rt][i] = (short)hb;
                Al[rt][i] = (short)lb;
            }
        }
#pragma unroll
        for (int ct = 0; ct < 6; ++ct) {
            int off = ((ks * 6 + ct) << 9) + (l << 3);
            short8 bh = *(const short8*)&BH[off];
            short8 bl = *(const short8*)&BL[off];
#pragma unroll
            for (int rt = 0; rt < 2; ++rt) {
                acc[rt][ct] = __builtin_amdgcn_mfma_f32_16x16x32_bf16(Ah[rt], bh, acc[rt][ct], 0, 0, 0);
                acc[rt][ct] = __builtin_amdgcn_mfma_f32_16x16x32_bf16(Al[rt], bh, acc[rt][ct], 0, 0, 0);
                acc[rt][ct] = __builtin_amdgcn_mfma_f32_16x16x32_bf16(Ah[rt], bl, acc[rt][ct], 0, 0, 0);
            }
        }
    }

#pragma unroll
    for (int rt = 0; rt < 2; ++rt) {
#pragma unroll
        for (int i = 0; i < 4; ++i) {
            int row = r0 + rt * 16 + ((l >> 4) << 2) + i;
            if (row < n) {
                float dv = dinv[row];
#pragma unroll
                for (int ct = 0; ct < 6; ++ct) {
                    float v = acc[rt][ct][i] * dv;
                    hs[(size_t)row * NCH + ct * 16 + (l & 15)] = (ushort_t)bf16_rne(v);
                }
            }
        }
    }
}

// ---------------------------------------------------------------------------
// MFMA GEMM (split-bf16): hs[r][c] = bf16((in[r][:]@W[:][c]) * dinv[r])
// BN params computed in-prologue from sums/g/bt; relu(t*a+b) on A-load
// ---------------------------------------------------------------------------
template <int K>
__global__ __launch_bounds__(256) void gemm_mfma_bn(const float* __restrict__ x,
                                                    const float* __restrict__ sums,
                                                    const float* __restrict__ g,
                                                    const float* __restrict__ bt,
                                                    float fn,
                                                    const float* __restrict__ W,
                                                    const float* __restrict__ dinv,
                                                    ushort_t* __restrict__ hs, int n) {
    constexpr int NKS = K / 32;
    constexpr int NFR = NKS * 6 * 512;
    __shared__ short BH[NFR];
    __shared__ short BL[NFR];
    __shared__ float ABl[2 * NCH];

    const int tid = threadIdx.x;
    for (int w = tid; w < K * NCH; w += 256) {
        float wv = W[w];
        int k = w / NCH;
        int col = w - k * NCH;
        int ks = k >> 5, kin = k & 31;
        int idx = ((ks * 6 + (col >> 4)) << 9) + (((kin >> 3) * 16 + (col & 15)) << 3) + (kin & 7);
        uint_t hb = bf16_rne(wv);
        float hf = __builtin_bit_cast(float, hb << 16);
        uint_t lb = bf16_rne(wv - hf);
        BH[idx] = (short)hb;
        BL[idx] = (short)lb;
    }
    if (tid < NCH) {
        float mean = sums[tid] / fn;
        float var = sums[NCH + tid] / fn - mean * mean;
        float a = g[tid] * rsqrtf(var + 1e-5f);
        ABl[tid] = a;
        ABl[NCH + tid] = bt[tid] - mean * a;
    }
    __syncthreads();

    const int l  = tid & 63;
    const int wv_ = tid >> 6;
    const int r0 = blockIdx.x * 128 + wv_ * 32;
    const int klo = (l >> 4) << 3;

    f32x4 acc[2][6] = {};

    for (int ks = 0; ks < NKS; ++ks) {
        float av[8], bv[8];
        int kb = ks * 32 + klo;
#pragma unroll
        for (int i = 0; i < 8; ++i) { av[i] = ABl[kb + i]; bv[i] = ABl[NCH + kb + i]; }
        short8 Ah[2], Al[2];
#pragma unroll
        for (int rt = 0; rt < 2; ++rt) {
            int rg = r0 + rt * 16 + (l & 15);
            rg = rg < n ? rg : n - 1;
            const float* px = x + (size_t)rg * K + ks * 32 + klo;
            float4 f0 = *(const float4*)px;
            float4 f1 = *(const float4*)(px + 4);
            float vv[8] = {f0.x, f0.y, f0.z, f0.w, f1.x, f1.y, f1.z, f1.w};
#pragma unroll
            for (int i = 0; i < 8; ++i) {
                float v = fmaxf(fmaf(vv[i], av[i], bv[i]), 0.0f);
                uint_t hb = bf16_rne(v);
                float hf = __builtin_bit_cast(float, hb << 16);
                uint_t lb = bf16_rne(v - hf);
                Ah[rt][i] = (short)hb;
                Al[rt][i] = (short)lb;
            }
        }
#pragma unroll
        for (int ct = 0; ct < 6; ++ct) {
            int off = ((ks * 6 + ct) << 9) + (l << 3);
            short8 bh = *(const short8*)&BH[off];
            short8 bl = *(const short8*)&BL[off];
#pragma unroll
            for (int rt = 0; rt < 2; ++rt) {
                acc[rt][ct] = __builtin_amdgcn_mfma_f32_16x16x32_bf16(Ah[rt], bh, acc[rt][ct], 0, 0, 0);
                acc[rt][ct] = __builtin_amdgcn_mfma_f32_16x16x32_bf16(Al[rt], bh, acc[rt][ct], 0, 0, 0);
                acc[rt][ct] = __builtin_amdgcn_mfma_f32_16x16x32_bf16(Ah[rt], bl, acc[rt][ct], 0, 0, 0);
            }
        }
    }

#pragma unroll
    for (int rt = 0; rt < 2; ++rt) {
#pragma unroll
        for (int i = 0; i < 4; ++i) {
            int row = r0 + rt * 16 + ((l >> 4) << 2) + i;
            if (row < n) {
                float dv = dinv[row];
#pragma unroll
                for (int ct = 0; ct < 6; ++ct) {
                    float v = acc[rt][ct][i] * dv;
                    hs[(size_t)row * NCH + ct * 16 + (l & 15)] = (ushort_t)bf16_rne(v);
                }
            }
        }
    }
}

// ---------------------------------------------------------------------------
// gather + fused BN stats (round-12 measured form): half-wave per node,
// lanes 0..23 hold uint2 (4 ch each); float4 coalesced AGG write;
// per-block LDS reduce -> 192 atomics/block (non-returning, low contention).
// grid = 2048 blocks (8/CU) for TLP; grid-stride loop.
// ---------------------------------------------------------------------------
__global__ __launch_bounds__(256) void gather_stats(const int* __restrict__ rowptr,
                                                    const int* __restrict__ adj,
                                                    const float* __restrict__ dinv,
                                                    const ushort_t* __restrict__ HS,
                                                    float* __restrict__ AGG,
                                                    float* __restrict__ sums, int n) {
    const int tid = threadIdx.x;
    const int hw = tid >> 5;         // 0..7
    const int lane = tid & 31;       // 0..31
    const bool act = lane < 24;
    const uint_t* HSu = (const uint_t*)HS;
    const int l2 = lane * 2;

    float4 s1 = make_float4(0.f, 0.f, 0.f, 0.f);
    float4 s2 = make_float4(0.f, 0.f, 0.f, 0.f);

    for (int node = blockIdx.x * 8 + hw; node < n; node += gridDim.x * 8) {
        if (act) {
            int lo = rowptr[node], hi = rowptr[node + 1];
            float dv = dinv[node];
            float4 a = unp(*(const uint2*)(HSu + (size_t)node * 48 + l2));  // self
            float4 b = make_float4(0.f, 0.f, 0.f, 0.f);
            int j = lo;
            for (; j + 1 < hi; j += 2) {
                int s0 = adj[j], s1i = adj[j + 1];
                float4 v0 = unp(*(const uint2*)(HSu + (size_t)s0 * 48 + l2));
                float4 v1 = unp(*(const uint2*)(HSu + (size_t)s1i * 48 + l2));
                a.x += v0.x; a.y += v0.y; a.z += v0.z; a.w += v0.w;
                b.x += v1.x; b.y += v1.y; b.z += v1.z; b.w += v1.w;
            }
            if (j < hi) {
                int s0 = adj[j];
                float4 v0 = unp(*(const uint2*)(HSu + (size_t)s0 * 48 + l2));
                a.x += v0.x; a.y += v0.y; a.z += v0.z; a.w += v0.w;
            }
            a.x = (a.x + b.x) * dv;
            a.y = (a.y + b.y) * dv;
            a.z = (a.z + b.z) * dv;
            a.w = (a.w + b.w) * dv;
            ((float4*)(AGG + (size_t)node * NCH))[lane] = a;
            s1.x += a.x; s1.y += a.y; s1.z += a.z; s1.w += a.w;
            s2.x = fmaf(a.x, a.x, s2.x); s2.y = fmaf(a.y, a.y, s2.y);
            s2.z = fmaf(a.z, a.z, s2.z); s2.w = fmaf(a.w, a.w, s2.w);
        }
    }

    __shared__ float R1[8][NCH], R2[8][NCH];
    if (act) {
        *(float4*)&R1[hw][lane * 4] = s1;
        *(float4*)&R2[hw][lane * 4] = s2;
    }
    __syncthreads();
    if (tid < NCH) {
        float a = 0.f, b = 0.f;
#pragma unroll
        for (int h = 0; h < 8; ++h) { a += R1[h][tid]; b += R2[h][tid]; }
        atomicAdd(&sums[tid], a);       // 1 atomic per address per block
        atomicAdd(&sums[NCH + tid], b);
    }
}

// fused BN-param + BN-apply + ReLU + column-sum pool (y never materialized)
__global__ __launch_bounds__(384) void apply_pool_kernel(const float* __restrict__ t,
                                                         const float* __restrict__ sums,
                                                         const float* __restrict__ g,
                                                         const float* __restrict__ bt,
                                                         float fn,
                                                         float* __restrict__ pool, int n) {
    int c = threadIdx.x, ry = threadIdx.y;
    __shared__ float A[NCH], B[NCH];
    if (ry == 0) {
        float mean = sums[c] / fn;
        float var = sums[NCH + c] / fn - mean * mean;
        float a = g[c] * rsqrtf(var + 1e-5f);
        A[c] = a;
        B[c] = bt[c] - mean * a;
    }
    __syncthreads();
    float a = A[c], b = B[c];
    float s = 0.f;
    for (int r = blockIdx.x * 4 + ry; r < n; r += gridDim.x * 4) {
        float v = t[(size_t)r * NCH + c];
        s += fmaxf(fmaf(v, a, b), 0.f);
    }
    __shared__ float L[4][NCH];
    L[ry][c] = s;
    __syncthreads();
    if (ry == 0) atomicAdd(&pool[c], L[0][c] + L[1][c] + L[2][c] + L[3][c]);
}

// tiny MLP head: 96 -> 128 -> 64 -> 32 -> 1
__global__ __launch_bounds__(128) void mlp_kernel(const float* __restrict__ pool,
        const float* __restrict__ fw1, const float* __restrict__ fb1,
        const float* __restrict__ fw2, const float* __restrict__ fb2,
        const float* __restrict__ fw3, const float* __restrict__ fb3,
        const float* __restrict__ fw4, const float* __restrict__ fb4,
        float* __restrict__ out, float invn) {
    __shared__ float v[NCH], l1[128], l2[64], l3[32];
    int t = threadIdx.x;
    if (t < NCH) v[t] = pool[t] * invn;
    __syncthreads();
    {
        float a = fb1[t];
        for (int k = 0; k < NCH; ++k) a = fmaf(v[k], fw1[k * 128 + t], a);
        l1[t] = fmaxf(a, 0.f);
    }
    __syncthreads();
    if (t < 64) {
        float a = fb2[t];
        for (int k = 0; k < 128; ++k) a = fmaf(l1[k], fw2[k * 64 + t], a);
        l2[t] = fmaxf(a, 0.f);
    }
    __syncthreads();
    if (t < 32) {
        float a = fb3[t];
        for (int k = 0; k < 64; ++k) a = fmaf(l2[k], fw3[k * 32 + t], a);
        l3[t] = fmaxf(a, 0.f);
    }
    __syncthreads();
    if (t == 0) {
        float a = fb4[0];
        for (int k = 0; k < 32; ++k) a = fmaf(l3[k], fw4[k], a);
        out[0] = a;
    }
}

// ---------------------------------------------------------------------------
extern "C" void kernel_launch(void* const* d_in, const int* in_sizes, int n_in,
                              void* d_out, int out_size, void* d_ws, size_t ws_size,
                              hipStream_t stream) {
    const float* x  = (const float*)d_in[0];
    const int*  ei  = (const int*)d_in[1];
    const float* W1 = (const float*)d_in[2];
    // b1/b2/b3 cancel in BatchNorm mean subtraction — unused
    const float* W2 = (const float*)d_in[4];
    const float* W3 = (const float*)d_in[6];
    const float* g1 = (const float*)d_in[8],  *bt1 = (const float*)d_in[9];
    const float* g2 = (const float*)d_in[10], *bt2 = (const float*)d_in[11];
    const float* g3 = (const float*)d_in[12], *bt3 = (const float*)d_in[13];
    const float* fw1 = (const float*)d_in[14], *fb1 = (const float*)d_in[15];
    const float* fw2 = (const float*)d_in[16], *fb2 = (const float*)d_in[17];
    const float* fw3 = (const float*)d_in[18], *fb3 = (const float*)d_in[19];
    const float* fw4 = (const float*)d_in[20], *fb4 = (const float*)d_in[21];
    float* out = (float*)d_out;

    const int N = in_sizes[0] / 128;
    const int E = in_sizes[1] / 2;
    const size_t n96 = (size_t)N * NCH;

    // workspace layout
    float* ws    = (float*)d_ws;
    float* T     = ws;                       // fp32 aggregate   N*96
    ushort_t* HSB = (ushort_t*)(T + n96);    // bf16 hs          N*96
    float* dinv  = T + n96 + n96 / 2;        // N
    float* sums1 = dinv + N;                 // 192
    float* sums2 = sums1 + 2 * NCH;          // 192
    float* sums3 = sums2 + 2 * NCH;          // 192
    float* pool  = sums3 + 2 * NCH;          // 96
    int*   cnt   = (int*)(pool + NCH);       // N (degree -> fill cursor)
    int*   rowptr= cnt + N;                  // N+1
    int*   bsum  = rowptr + N + 1;           // 256
    int*   adj   = bsum + 256;               // E
    const int nsmall = 3 * 2 * NCH + NCH;    // sums1..3 + pool

    dim3 b96(NCH, 4);
    const int gemmGrid = (N + 127) / 128;
    const int fillGrid = (E + 255) / 256;
    const int nb = (N + SCAN_TILE - 1) / SCAN_TILE;

    // ---- CSR build + dinv ----
    hipMemsetAsync(sums1, 0, (size_t)nsmall * 4, stream);
    hipMemsetAsync(cnt, 0, (size_t)N * 4, stream);
    count_kernel<<<(E + 255) / 256, 256, 0, stream>>>(ei + E, cnt, E);
    scanA_kernel<<<nb, 256, 0, stream>>>(cnt, bsum, N);
    scanB_kernel<<<1, 256, 0, stream>>>(bsum, rowptr + N, nb);
    scanC_kernel<<<nb, 256, 0, stream>>>(cnt, bsum, rowptr, dinv, N);

    // ---- layer 1 GEMM overlapped with adj fill (both depend only on scanC) ----
    gemm1_fill<<<gemmGrid + fillGrid, 256, 0, stream>>>(x, W1, dinv, HSB, N, gemmGrid,
                                                        ei, cnt, adj, E);
    gather_stats<<<2048, 256, 0, stream>>>(rowptr, adj, dinv, HSB, T, sums1, N);

    // ---- layer 2: 96 -> 96 (BN-param + BN+ReLU fused into GEMM) ----
    gemm_mfma_bn<96><<<gemmGrid, 256, 0, stream>>>(T, sums1, g1, bt1, (float)N,
                                                   W2, dinv, HSB, N);
    gather_stats<<<2048, 256, 0, stream>>>(rowptr, adj, dinv, HSB, T, sums2, N);

    // ---- layer 3: 96 -> 96 ----
    gemm_mfma_bn<96><<<gemmGrid, 256, 0, stream>>>(T, sums2, g2, bt2, (float)N,
                                                   W3, dinv, HSB, N);
    gather_stats<<<2048, 256, 0, stream>>>(rowptr, adj, dinv, HSB, T, sums3, N);

    // ---- fused BN-param + apply + pool, then MLP head ----
    apply_pool_kernel<<<512, b96, 0, stream>>>(T, sums3, g3, bt3, (float)N, pool, N);
    mlp_kernel<<<1, 128, 0, stream>>>(pool, fw1, fb1, fw2, fb2, fw3, fb3,
                                      fw4, fb4, out, 1.0f / (float)N);
}